// Round 3
// baseline (528.760 us; speedup 1.0000x reference)
//
#include <hip/hip_runtime.h>
#include <hip/hip_bf16.h>

// GroupedMLP: E=8, H=1024, I=2816, T=8192. fp32 in HBM, bf16 MFMA compute.
//   0) convx:  X fp32 -> xb bf16 (staged inside d_out; gemm3 overwrites later)
//   1) tconv<H,I> gate -> gateT bf16 [E,I,H]  (zero-LDS register transpose)
//   2) tconv<H,I> up   -> upT
//   3) gemm12: inter = silu(xb@gate)*(xb@up), bf16 (m97-style, BM128 BN64 x2 outputs)
//   4) tconv<I,H> down -> downT (reuses gateT region)
//   5) gemm3: out = inter @ down -> fp32 (m97-exact 128x128)
// ws: 3 x 46,137,344 B = 138,412,032 B (round-1 verified available).

#define E_ 8
#define H_ 1024
#define I_ 2816
#define T_ 8192

typedef unsigned short u16;
typedef __attribute__((ext_vector_type(8))) short s16x8;
typedef __attribute__((ext_vector_type(8))) unsigned short u16x8;
typedef __attribute__((ext_vector_type(4))) float f32x4;

__device__ __forceinline__ void async16(const u16* g, u16* l) {
  __builtin_amdgcn_global_load_lds((__attribute__((address_space(1))) void*)g,
                                   (__attribute__((address_space(3))) void*)l, 16, 0, 0);
}

__device__ __forceinline__ u16 f2b(float f) {
  union { __hip_bfloat16 h; u16 u; } c;
  c.h = __float2bfloat16(f);
  return c.u;
}

// ---------------- convert X fp32 -> bf16, 8 elems/thread ----------------
__global__ __launch_bounds__(256) void convx_k(const float* __restrict__ x,
                                               u16* __restrict__ xb) {
  size_t i = ((size_t)blockIdx.x * 256 + threadIdx.x) * 8;
  float4 v0 = *(const float4*)(x + i);
  float4 v1 = *(const float4*)(x + i + 4);
  u16x8 b;
  b[0] = f2b(v0.x); b[1] = f2b(v0.y); b[2] = f2b(v0.z); b[3] = f2b(v0.w);
  b[4] = f2b(v1.x); b[5] = f2b(v1.y); b[6] = f2b(v1.z); b[7] = f2b(v1.w);
  *(u16x8*)(xb + i) = b;
}

// ------- zero-LDS transpose+convert: out[c][r] bf16 = in[r][c] fp32 -------
// Block: 256 columns (one per lane) x 64 rows. Reads: 256B/wave coalesced.
// Stores: u16x8 per lane; each lane fills two whole 64B lines (L2-merged).
template <int R, int C>
__global__ __launch_bounds__(256) void tconv_k(const float* __restrict__ in,
                                               u16* __restrict__ out) {
  const int t = threadIdx.x;
  const size_t eoff = (size_t)blockIdx.z * (size_t)R * (size_t)C;
  const int c = blockIdx.x * 256 + t;
  const int r0 = blockIdx.y * 64;
  const float* p = in + eoff + (size_t)r0 * C + c;
  u16* o = out + eoff + (size_t)c * R + r0;
#pragma unroll
  for (int q = 0; q < 8; ++q) {
    float v[8];
#pragma unroll
    for (int j = 0; j < 8; ++j) v[j] = p[(size_t)(8 * q + j) * C];
    u16x8 b;
#pragma unroll
    for (int j = 0; j < 8; ++j) b[j] = f2b(v[j]);
    *(u16x8*)(o + 8 * q) = b;
  }
}

// ---------------- fused gate/up GEMM + SwiGLU ----------------
__global__ __launch_bounds__(256, 2) void gemm12_k(
    const u16* __restrict__ X, const u16* __restrict__ GT,
    const u16* __restrict__ UT, const int* __restrict__ tpe,
    u16* __restrict__ inter) {
  __shared__ u16 sA[128 * 32];
  __shared__ u16 sG[64 * 32];
  __shared__ u16 sU[64 * 32];
  const int t = threadIdx.x;
  const int m0 = blockIdx.y * 128;
  const int n0 = blockIdx.x * 64;

  int e = 0, seg_end = T_;
  {
    int s = 0;
    for (int i = 0; i < E_; ++i) {
      int c = tpe[i];
      if (m0 < s + c) { e = i; seg_end = s + c; break; }
      s += c;
    }
  }
  const u16* GTe = GT + (size_t)e * I_ * H_;
  const u16* UTe = UT + (size_t)e * I_ * H_;

  const u16* gA0 = X + (size_t)(m0 + (t >> 2)) * H_ + (t & 3) * 8;
  const u16* gA1 = gA0 + (size_t)64 * H_;
  const u16* gG  = GTe + (size_t)(n0 + (t >> 2)) * H_ + (t & 3) * 8;
  const u16* gU  = UTe + (size_t)(n0 + (t >> 2)) * H_ + (t & 3) * 8;
  u16* lA = sA + t * 8;
  u16* lG = sG + t * 8;
  u16* lU = sU + t * 8;

  const int l = t & 63, w = t >> 6;
  const int wm = (w & 1) * 64, wn = (w >> 1) * 32;
  const u16* fA = sA + (size_t)(wm + (l & 15)) * 32 + (l >> 4) * 8;
  const u16* fG = sG + (size_t)(wn + (l & 15)) * 32 + (l >> 4) * 8;
  const u16* fU = sU + (size_t)(wn + (l & 15)) * 32 + (l >> 4) * 8;

  f32x4 accG[4][2], accU[4][2];
#pragma unroll
  for (int mi = 0; mi < 4; ++mi)
#pragma unroll
    for (int ni = 0; ni < 2; ++ni) {
      accG[mi][ni] = (f32x4){0.f, 0.f, 0.f, 0.f};
      accU[mi][ni] = (f32x4){0.f, 0.f, 0.f, 0.f};
    }

  for (int k0 = 0; k0 < H_; k0 += 32) {
    async16(gA0 + k0, lA);
    async16(gA1 + k0, lA + 2048);
    async16(gG + k0, lG);
    async16(gU + k0, lU);
    __syncthreads();
    s16x8 aF[4], gF[2], uF[2];
#pragma unroll
    for (int mi = 0; mi < 4; ++mi) aF[mi] = *(const s16x8*)(fA + mi * 512);
#pragma unroll
    for (int ni = 0; ni < 2; ++ni) {
      gF[ni] = *(const s16x8*)(fG + ni * 512);
      uF[ni] = *(const s16x8*)(fU + ni * 512);
    }
#pragma unroll
    for (int mi = 0; mi < 4; ++mi)
#pragma unroll
      for (int ni = 0; ni < 2; ++ni) {
        accG[mi][ni] = __builtin_amdgcn_mfma_f32_16x16x32_bf16(aF[mi], gF[ni], accG[mi][ni], 0, 0, 0);
        accU[mi][ni] = __builtin_amdgcn_mfma_f32_16x16x32_bf16(aF[mi], uF[ni], accU[mi][ni], 0, 0, 0);
      }
    __syncthreads();
  }

  const int colb = l & 15, rowb = (l >> 4) * 4;
#pragma unroll
  for (int mi = 0; mi < 4; ++mi)
#pragma unroll
    for (int ni = 0; ni < 2; ++ni) {
      const size_t gcol = (size_t)(n0 + wn + ni * 16 + colb);
#pragma unroll
      for (int r = 0; r < 4; ++r) {
        int grow = m0 + wm + mi * 16 + rowb + r;
        if (grow < seg_end) {
          float o1 = accG[mi][ni][r];
          float o2 = accU[mi][ni][r];
          float sv = o1 / (1.f + __expf(-o1));
          inter[(size_t)grow * I_ + gcol] = f2b(sv * o2);
        }
      }
    }
}

// ---------------- down-proj GEMM (m97-exact 128x128 tile), fp32 out ----------------
__global__ __launch_bounds__(256, 2) void gemm3_k(
    const u16* __restrict__ A, const u16* __restrict__ DT,
    const int* __restrict__ tpe, float* __restrict__ out) {
  __shared__ u16 sA[128 * 32];
  __shared__ u16 sB[128 * 32];
  const int t = threadIdx.x;
  const int m0 = blockIdx.y * 128;
  const int n0 = blockIdx.x * 128;

  int e = 0, seg_end = T_;
  {
    int s = 0;
    for (int i = 0; i < E_; ++i) {
      int c = tpe[i];
      if (m0 < s + c) { e = i; seg_end = s + c; break; }
      s += c;
    }
  }
  const u16* DTe = DT + (size_t)e * H_ * I_;

  const u16* gA0 = A + (size_t)(m0 + (t >> 2)) * I_ + (t & 3) * 8;
  const u16* gA1 = gA0 + (size_t)64 * I_;
  const u16* gB0 = DTe + (size_t)(n0 + (t >> 2)) * I_ + (t & 3) * 8;
  const u16* gB1 = gB0 + (size_t)64 * I_;
  u16* lA = sA + t * 8;
  u16* lB = sB + t * 8;

  const int l = t & 63, w = t >> 6;
  const int wm = (w & 1) * 64, wn = (w >> 1) * 64;
  const u16* fA = sA + (size_t)(wm + (l & 15)) * 32 + (l >> 4) * 8;
  const u16* fB = sB + (size_t)(wn + (l & 15)) * 32 + (l >> 4) * 8;

  f32x4 acc[4][4];
#pragma unroll
  for (int mi = 0; mi < 4; ++mi)
#pragma unroll
    for (int ni = 0; ni < 4; ++ni) acc[mi][ni] = (f32x4){0.f, 0.f, 0.f, 0.f};

  for (int k0 = 0; k0 < I_; k0 += 32) {
    async16(gA0 + k0, lA);
    async16(gA1 + k0, lA + 2048);
    async16(gB0 + k0, lB);
    async16(gB1 + k0, lB + 2048);
    __syncthreads();
    s16x8 aF[4], bF[4];
#pragma unroll
    for (int mi = 0; mi < 4; ++mi) aF[mi] = *(const s16x8*)(fA + mi * 512);
#pragma unroll
    for (int ni = 0; ni < 4; ++ni) bF[ni] = *(const s16x8*)(fB + ni * 512);
#pragma unroll
    for (int mi = 0; mi < 4; ++mi)
#pragma unroll
      for (int ni = 0; ni < 4; ++ni)
        acc[mi][ni] = __builtin_amdgcn_mfma_f32_16x16x32_bf16(aF[mi], bF[ni], acc[mi][ni], 0, 0, 0);
    __syncthreads();
  }

  const int colb = l & 15, rowb = (l >> 4) * 4;
#pragma unroll
  for (int mi = 0; mi < 4; ++mi)
#pragma unroll
    for (int ni = 0; ni < 4; ++ni) {
      const size_t gcol = (size_t)(n0 + wn + ni * 16 + colb);
#pragma unroll
      for (int r = 0; r < 4; ++r) {
        int grow = m0 + wm + mi * 16 + rowb + r;
        if (grow < seg_end) out[(size_t)grow * H_ + gcol] = acc[mi][ni][r];
      }
    }
}

extern "C" void kernel_launch(void* const* d_in, const int* in_sizes, int n_in,
                              void* d_out, int out_size, void* d_ws, size_t ws_size,
                              hipStream_t stream) {
  const float* X = (const float*)d_in[0];
  const float* G = (const float*)d_in[1];
  const float* U = (const float*)d_in[2];
  const float* D = (const float*)d_in[3];
  const int* tpe = (const int*)d_in[4];
  float* out = (float*)d_out;

  const size_t W = (size_t)E_ * H_ * I_;
  if (ws_size < 3 * W * sizeof(u16)) return;
  u16* r0 = (u16*)d_ws;   // gateT, later downT
  u16* r1 = r0 + W;       // upT
  u16* r2 = r1 + W;       // inter [T][I] bf16
  u16* xb = (u16*)d_out;  // bf16 X staged in d_out; gemm3 overwrites

  convx_k<<<dim3((T_ * H_) / (256 * 8)), 256, 0, stream>>>(X, xb);
  tconv_k<H_, I_><<<dim3(I_ / 256, H_ / 64, E_), 256, 0, stream>>>(G, r0);
  tconv_k<H_, I_><<<dim3(I_ / 256, H_ / 64, E_), 256, 0, stream>>>(U, r1);
  gemm12_k<<<dim3(I_ / 64, T_ / 128), 256, 0, stream>>>(xb, r0, r1, tpe, r2);
  tconv_k<I_, H_><<<dim3(H_ / 256, I_ / 64, E_), 256, 0, stream>>>(D, r0);
  gemm3_k<<<dim3(H_ / 128, T_ / 128), 256, 0, stream>>>(r2, r0, tpe, out);
}

// Round 4
// 489.524 us; speedup vs baseline: 1.0801x; 1.0801x over previous
//
#include <hip/hip_runtime.h>
#include <hip/hip_bf16.h>

// GroupedMLP: E=8, H=1024, I=2816, T=8192. fp32 in HBM, bf16 MFMA compute.
//   0) convx:   X fp32 -> xb bf16 (staged inside d_out; gemm3 overwrites later)
//   1) tconvGU: gate+up [E,H,I] fp32 -> gateT/upT bf16 [E,I,H] (one launch, z=16)
//   2) gemm12:  inter = silu(xb@gate)*(xb@up), bf16 (m97-style; ANCHOR - unchanged)
//   3) tconvD:  down [E,I,H] fp32 -> downT bf16 [E,H,I] (reuses gateT region)
//   4) gemm3:   out = inter @ down -> fp32 (m97-exact 128x128; unchanged)
// tconv uses an XOR-swizzled fp32 LDS tile (addr = r*64 + (c^r)): conflict-free
// (exactly 2-way) on both LDS phases, fully coalesced on both global phases.
// ws: 3 x 46,137,344 B = 138,412,032 B.

#define E_ 8
#define H_ 1024
#define I_ 2816
#define T_ 8192

typedef unsigned short u16;
typedef __attribute__((ext_vector_type(8))) short s16x8;
typedef __attribute__((ext_vector_type(8))) unsigned short u16x8;
typedef __attribute__((ext_vector_type(4))) float f32x4;

__device__ __forceinline__ void async16(const u16* g, u16* l) {
  __builtin_amdgcn_global_load_lds((__attribute__((address_space(1))) void*)g,
                                   (__attribute__((address_space(3))) void*)l, 16, 0, 0);
}

__device__ __forceinline__ u16 f2b(float f) {
  union { __hip_bfloat16 h; u16 u; } c;
  c.h = __float2bfloat16(f);
  return c.u;
}

// ---------------- convert X fp32 -> bf16, 8 elems/thread ----------------
__global__ __launch_bounds__(256) void convx_k(const float* __restrict__ x,
                                               u16* __restrict__ xb) {
  size_t i = ((size_t)blockIdx.x * 256 + threadIdx.x) * 8;
  float4 v0 = *(const float4*)(x + i);
  float4 v1 = *(const float4*)(x + i + 4);
  u16x8 b;
  b[0] = f2b(v0.x); b[1] = f2b(v0.y); b[2] = f2b(v0.z); b[3] = f2b(v0.w);
  b[4] = f2b(v1.x); b[5] = f2b(v1.y); b[6] = f2b(v1.z); b[7] = f2b(v1.w);
  *(u16x8*)(xb + i) = b;
}

// -------- swizzled-LDS transpose+convert core: out[c][r] bf16 = in[r][c] fp32 --------
// 64x64 tile. Phase1: float4 row loads -> swizzled scalar LDS writes (2-way, free).
// Phase2: swizzled scalar LDS gather (2-way, free) -> u16x8 column stores where
// 4 lanes x 16B cover each 64B line fully (16 full lines / instr).
template <int R, int C>
__device__ __forceinline__ void tconv_tile(const float* __restrict__ in,
                                           u16* __restrict__ out,
                                           int bx, int by, int t) {
  __shared__ float tile[64 * 64];
  const int c0 = bx * 64, r0 = by * 64;
  {
    const int rr = t >> 4;          // 0..15
    const int c4 = (t & 15) * 4;    // 0..60
#pragma unroll
    for (int j = 0; j < 4; ++j) {
      const int r = rr + 16 * j;
      float4 v = *(const float4*)(in + (size_t)(r0 + r) * C + c0 + c4);
      tile[r * 64 + ((c4 + 0) ^ r)] = v.x;
      tile[r * 64 + ((c4 + 1) ^ r)] = v.y;
      tile[r * 64 + ((c4 + 2) ^ r)] = v.z;
      tile[r * 64 + ((c4 + 3) ^ r)] = v.w;
    }
  }
  __syncthreads();
  {
    const int c = t >> 2;           // 0..63
    const int rq = (t & 3) * 8;     // 0,8,16,24
    u16* o = out + (size_t)(c0 + c) * R + r0;
    u16x8 b;
#pragma unroll
    for (int j = 0; j < 8; ++j) {
      const int r = rq + j;
      b[j] = f2b(tile[r * 64 + (c ^ r)]);
    }
    *(u16x8*)(o + rq) = b;
#pragma unroll
    for (int j = 0; j < 8; ++j) {
      const int r = 32 + rq + j;
      b[j] = f2b(tile[r * 64 + (c ^ r)]);
    }
    *(u16x8*)(o + 32 + rq) = b;
  }
}

// gate+up in one launch: z = expert*2 + (0=gate,1=up)
__global__ __launch_bounds__(256) void tconvGU_k(const float* __restrict__ G,
                                                 const float* __restrict__ U,
                                                 u16* __restrict__ GT,
                                                 u16* __restrict__ UT) {
  const int z = blockIdx.z;
  const size_t eoff = (size_t)(z >> 1) * (size_t)H_ * I_;
  const float* in = ((z & 1) ? U : G) + eoff;
  u16* out = ((z & 1) ? UT : GT) + eoff;
  tconv_tile<H_, I_>(in, out, blockIdx.x, blockIdx.y, threadIdx.x);
}

__global__ __launch_bounds__(256) void tconvD_k(const float* __restrict__ D,
                                                u16* __restrict__ DT) {
  const size_t eoff = (size_t)blockIdx.z * (size_t)H_ * I_;
  tconv_tile<I_, H_>(D + eoff, DT + eoff, blockIdx.x, blockIdx.y, threadIdx.x);
}

// ---------------- fused gate/up GEMM + SwiGLU (ANCHOR - unchanged) ----------------
__global__ __launch_bounds__(256, 2) void gemm12_k(
    const u16* __restrict__ X, const u16* __restrict__ GT,
    const u16* __restrict__ UT, const int* __restrict__ tpe,
    u16* __restrict__ inter) {
  __shared__ u16 sA[128 * 32];
  __shared__ u16 sG[64 * 32];
  __shared__ u16 sU[64 * 32];
  const int t = threadIdx.x;
  const int m0 = blockIdx.y * 128;
  const int n0 = blockIdx.x * 64;

  int e = 0, seg_end = T_;
  {
    int s = 0;
    for (int i = 0; i < E_; ++i) {
      int c = tpe[i];
      if (m0 < s + c) { e = i; seg_end = s + c; break; }
      s += c;
    }
  }
  const u16* GTe = GT + (size_t)e * I_ * H_;
  const u16* UTe = UT + (size_t)e * I_ * H_;

  const u16* gA0 = X + (size_t)(m0 + (t >> 2)) * H_ + (t & 3) * 8;
  const u16* gA1 = gA0 + (size_t)64 * H_;
  const u16* gG  = GTe + (size_t)(n0 + (t >> 2)) * H_ + (t & 3) * 8;
  const u16* gU  = UTe + (size_t)(n0 + (t >> 2)) * H_ + (t & 3) * 8;
  u16* lA = sA + t * 8;
  u16* lG = sG + t * 8;
  u16* lU = sU + t * 8;

  const int l = t & 63, w = t >> 6;
  const int wm = (w & 1) * 64, wn = (w >> 1) * 32;
  const u16* fA = sA + (size_t)(wm + (l & 15)) * 32 + (l >> 4) * 8;
  const u16* fG = sG + (size_t)(wn + (l & 15)) * 32 + (l >> 4) * 8;
  const u16* fU = sU + (size_t)(wn + (l & 15)) * 32 + (l >> 4) * 8;

  f32x4 accG[4][2], accU[4][2];
#pragma unroll
  for (int mi = 0; mi < 4; ++mi)
#pragma unroll
    for (int ni = 0; ni < 2; ++ni) {
      accG[mi][ni] = (f32x4){0.f, 0.f, 0.f, 0.f};
      accU[mi][ni] = (f32x4){0.f, 0.f, 0.f, 0.f};
    }

  for (int k0 = 0; k0 < H_; k0 += 32) {
    async16(gA0 + k0, lA);
    async16(gA1 + k0, lA + 2048);
    async16(gG + k0, lG);
    async16(gU + k0, lU);
    __syncthreads();
    s16x8 aF[4], gF[2], uF[2];
#pragma unroll
    for (int mi = 0; mi < 4; ++mi) aF[mi] = *(const s16x8*)(fA + mi * 512);
#pragma unroll
    for (int ni = 0; ni < 2; ++ni) {
      gF[ni] = *(const s16x8*)(fG + ni * 512);
      uF[ni] = *(const s16x8*)(fU + ni * 512);
    }
#pragma unroll
    for (int mi = 0; mi < 4; ++mi)
#pragma unroll
      for (int ni = 0; ni < 2; ++ni) {
        accG[mi][ni] = __builtin_amdgcn_mfma_f32_16x16x32_bf16(aF[mi], gF[ni], accG[mi][ni], 0, 0, 0);
        accU[mi][ni] = __builtin_amdgcn_mfma_f32_16x16x32_bf16(aF[mi], uF[ni], accU[mi][ni], 0, 0, 0);
      }
    __syncthreads();
  }

  const int colb = l & 15, rowb = (l >> 4) * 4;
#pragma unroll
  for (int mi = 0; mi < 4; ++mi)
#pragma unroll
    for (int ni = 0; ni < 2; ++ni) {
      const size_t gcol = (size_t)(n0 + wn + ni * 16 + colb);
#pragma unroll
      for (int r = 0; r < 4; ++r) {
        int grow = m0 + wm + mi * 16 + rowb + r;
        if (grow < seg_end) {
          float o1 = accG[mi][ni][r];
          float o2 = accU[mi][ni][r];
          float sv = o1 / (1.f + __expf(-o1));
          inter[(size_t)grow * I_ + gcol] = f2b(sv * o2);
        }
      }
    }
}

// ---------------- down-proj GEMM (m97-exact 128x128 tile), fp32 out ----------------
__global__ __launch_bounds__(256, 2) void gemm3_k(
    const u16* __restrict__ A, const u16* __restrict__ DT,
    const int* __restrict__ tpe, float* __restrict__ out) {
  __shared__ u16 sA[128 * 32];
  __shared__ u16 sB[128 * 32];
  const int t = threadIdx.x;
  const int m0 = blockIdx.y * 128;
  const int n0 = blockIdx.x * 128;

  int e = 0, seg_end = T_;
  {
    int s = 0;
    for (int i = 0; i < E_; ++i) {
      int c = tpe[i];
      if (m0 < s + c) { e = i; seg_end = s + c; break; }
      s += c;
    }
  }
  const u16* DTe = DT + (size_t)e * H_ * I_;

  const u16* gA0 = A + (size_t)(m0 + (t >> 2)) * I_ + (t & 3) * 8;
  const u16* gA1 = gA0 + (size_t)64 * I_;
  const u16* gB0 = DTe + (size_t)(n0 + (t >> 2)) * I_ + (t & 3) * 8;
  const u16* gB1 = gB0 + (size_t)64 * I_;
  u16* lA = sA + t * 8;
  u16* lB = sB + t * 8;

  const int l = t & 63, w = t >> 6;
  const int wm = (w & 1) * 64, wn = (w >> 1) * 64;
  const u16* fA = sA + (size_t)(wm + (l & 15)) * 32 + (l >> 4) * 8;
  const u16* fB = sB + (size_t)(wn + (l & 15)) * 32 + (l >> 4) * 8;

  f32x4 acc[4][4];
#pragma unroll
  for (int mi = 0; mi < 4; ++mi)
#pragma unroll
    for (int ni = 0; ni < 4; ++ni) acc[mi][ni] = (f32x4){0.f, 0.f, 0.f, 0.f};

  for (int k0 = 0; k0 < I_; k0 += 32) {
    async16(gA0 + k0, lA);
    async16(gA1 + k0, lA + 2048);
    async16(gB0 + k0, lB);
    async16(gB1 + k0, lB + 2048);
    __syncthreads();
    s16x8 aF[4], bF[4];
#pragma unroll
    for (int mi = 0; mi < 4; ++mi) aF[mi] = *(const s16x8*)(fA + mi * 512);
#pragma unroll
    for (int ni = 0; ni < 4; ++ni) bF[ni] = *(const s16x8*)(fB + ni * 512);
#pragma unroll
    for (int mi = 0; mi < 4; ++mi)
#pragma unroll
      for (int ni = 0; ni < 4; ++ni)
        acc[mi][ni] = __builtin_amdgcn_mfma_f32_16x16x32_bf16(aF[mi], bF[ni], acc[mi][ni], 0, 0, 0);
    __syncthreads();
  }

  const int colb = l & 15, rowb = (l >> 4) * 4;
#pragma unroll
  for (int mi = 0; mi < 4; ++mi)
#pragma unroll
    for (int ni = 0; ni < 4; ++ni) {
      const size_t gcol = (size_t)(n0 + wn + ni * 16 + colb);
#pragma unroll
      for (int r = 0; r < 4; ++r) {
        int grow = m0 + wm + mi * 16 + rowb + r;
        if (grow < seg_end) out[(size_t)grow * H_ + gcol] = acc[mi][ni][r];
      }
    }
}

extern "C" void kernel_launch(void* const* d_in, const int* in_sizes, int n_in,
                              void* d_out, int out_size, void* d_ws, size_t ws_size,
                              hipStream_t stream) {
  const float* X = (const float*)d_in[0];
  const float* G = (const float*)d_in[1];
  const float* U = (const float*)d_in[2];
  const float* D = (const float*)d_in[3];
  const int* tpe = (const int*)d_in[4];
  float* out = (float*)d_out;

  const size_t W = (size_t)E_ * H_ * I_;
  if (ws_size < 3 * W * sizeof(u16)) return;
  u16* r0 = (u16*)d_ws;   // gateT, later downT
  u16* r1 = r0 + W;       // upT
  u16* r2 = r1 + W;       // inter [T][I] bf16
  u16* xb = (u16*)d_out;  // bf16 X staged in d_out; gemm3 overwrites

  convx_k<<<dim3((T_ * H_) / (256 * 8)), 256, 0, stream>>>(X, xb);
  tconvGU_k<<<dim3(I_ / 64, H_ / 64, E_ * 2), 256, 0, stream>>>(G, U, r0, r1);
  gemm12_k<<<dim3(I_ / 64, T_ / 128), 256, 0, stream>>>(xb, r0, r1, tpe, r2);
  tconvD_k<<<dim3(H_ / 64, I_ / 64, E_), 256, 0, stream>>>(D, r0);
  gemm3_k<<<dim3(H_ / 128, T_ / 128), 256, 0, stream>>>(r2, r0, tpe, out);
}

// Round 5
// 486.614 us; speedup vs baseline: 1.0866x; 1.0060x over previous
//
#include <hip/hip_runtime.h>
#include <hip/hip_bf16.h>

// GroupedMLP: E=8, H=1024, I=2816, T=8192. fp32 in HBM, bf16 MFMA compute.
//   0) convx:   X fp32 -> xb bf16 (staged inside d_out; gemm3 overwrites later)
//   1) tconvGU: gate+up fp32 [E,H,I] -> gateT/upT bf16 [E,I,H]  (HBM-BW-bound, ~floor)
//   2) gemm12:  inter = silu(xb@gate)*(xb@up)  [BK=64, chunk-swizzled LDS]
//   3) tconvD:  down fp32 [E,I,H] -> downT bf16 [E,H,I] (reuses gateT region)
//   4) gemm3:   out = inter @ down, split-K x2 (ks0->out, ks1->r1 partial), BK=64
//   5) add_k:   out += r1 partial
// Chunk swizzle: LDS 16B-chunk for (row m, k-chunk j) lives at m*8 + (j ^ (m&7)).
// Staging stays lane-linear (global_load_lds constraint); reads hit all 32 banks
// in the minimal 8 phases per b128. ws: 3 x 46,137,344 B.

#define E_ 8
#define H_ 1024
#define I_ 2816
#define T_ 8192

typedef unsigned short u16;
typedef __attribute__((ext_vector_type(8))) short s16x8;
typedef __attribute__((ext_vector_type(8))) unsigned short u16x8;
typedef __attribute__((ext_vector_type(4))) float f32x4;

__device__ __forceinline__ void async16(const u16* g, u16* l) {
  __builtin_amdgcn_global_load_lds((__attribute__((address_space(1))) void*)g,
                                   (__attribute__((address_space(3))) void*)l, 16, 0, 0);
}

__device__ __forceinline__ u16 f2b(float f) {
  union { __hip_bfloat16 h; u16 u; } c;
  c.h = __float2bfloat16(f);
  return c.u;
}

// ---------------- convert X fp32 -> bf16 ----------------
__global__ __launch_bounds__(256) void convx_k(const float* __restrict__ x,
                                               u16* __restrict__ xb) {
  size_t i = ((size_t)blockIdx.x * 256 + threadIdx.x) * 8;
  float4 v0 = *(const float4*)(x + i);
  float4 v1 = *(const float4*)(x + i + 4);
  u16x8 b;
  b[0] = f2b(v0.x); b[1] = f2b(v0.y); b[2] = f2b(v0.z); b[3] = f2b(v0.w);
  b[4] = f2b(v1.x); b[5] = f2b(v1.y); b[6] = f2b(v1.z); b[7] = f2b(v1.w);
  *(u16x8*)(xb + i) = b;
}

// -------- swizzled-LDS transpose+convert (HBM-bound; unchanged from R4) --------
template <int R, int C>
__device__ __forceinline__ void tconv_tile(const float* __restrict__ in,
                                           u16* __restrict__ out,
                                           int bx, int by, int t) {
  __shared__ float tile[64 * 64];
  const int c0 = bx * 64, r0 = by * 64;
  {
    const int rr = t >> 4;
    const int c4 = (t & 15) * 4;
#pragma unroll
    for (int j = 0; j < 4; ++j) {
      const int r = rr + 16 * j;
      float4 v = *(const float4*)(in + (size_t)(r0 + r) * C + c0 + c4);
      tile[r * 64 + ((c4 + 0) ^ r)] = v.x;
      tile[r * 64 + ((c4 + 1) ^ r)] = v.y;
      tile[r * 64 + ((c4 + 2) ^ r)] = v.z;
      tile[r * 64 + ((c4 + 3) ^ r)] = v.w;
    }
  }
  __syncthreads();
  {
    const int c = t >> 2;
    const int rq = (t & 3) * 8;
    u16* o = out + (size_t)(c0 + c) * R + r0;
    u16x8 b;
#pragma unroll
    for (int j = 0; j < 8; ++j) {
      const int r = rq + j;
      b[j] = f2b(tile[r * 64 + (c ^ r)]);
    }
    *(u16x8*)(o + rq) = b;
#pragma unroll
    for (int j = 0; j < 8; ++j) {
      const int r = 32 + rq + j;
      b[j] = f2b(tile[r * 64 + (c ^ r)]);
    }
    *(u16x8*)(o + 32 + rq) = b;
  }
}

__global__ __launch_bounds__(256) void tconvGU_k(const float* __restrict__ G,
                                                 const float* __restrict__ U,
                                                 u16* __restrict__ GT,
                                                 u16* __restrict__ UT) {
  const int z = blockIdx.z;
  const size_t eoff = (size_t)(z >> 1) * (size_t)H_ * I_;
  const float* in = ((z & 1) ? U : G) + eoff;
  u16* out = ((z & 1) ? UT : GT) + eoff;
  tconv_tile<H_, I_>(in, out, blockIdx.x, blockIdx.y, threadIdx.x);
}

__global__ __launch_bounds__(256) void tconvD_k(const float* __restrict__ D,
                                                u16* __restrict__ DT) {
  const size_t eoff = (size_t)blockIdx.z * (size_t)H_ * I_;
  tconv_tile<I_, H_>(D + eoff, DT + eoff, blockIdx.x, blockIdx.y, threadIdx.x);
}

// ---------------- fused gate/up GEMM + SwiGLU, BK=64, chunk-swizzled ----------------
__global__ __launch_bounds__(256, 2) void gemm12_k(
    const u16* __restrict__ X, const u16* __restrict__ GT,
    const u16* __restrict__ UT, const int* __restrict__ tpe,
    u16* __restrict__ inter) {
  __shared__ u16 sA[128 * 64];  // [m][k] with chunk swizzle, 16 KB
  __shared__ u16 sG[64 * 64];   // 8 KB
  __shared__ u16 sU[64 * 64];   // 8 KB
  const int t = threadIdx.x;
  const int m0 = blockIdx.y * 128;
  const int n0 = blockIdx.x * 64;

  int e = 0, seg_end = T_;
  {
    int s = 0;
    for (int i = 0; i < E_; ++i) {
      int c = tpe[i];
      if (m0 < s + c) { e = i; seg_end = s + c; break; }
      s += c;
    }
  }
  const u16* GTe = GT + (size_t)e * I_ * H_;
  const u16* UTe = UT + (size_t)e * I_ * H_;

  // staging: thread t, round q -> row = q*32 + (t>>3), global k-chunk = (t&7)^((t>>3)&7)
  const int sj = ((t & 7) ^ ((t >> 3) & 7)) * 8;
  const u16* gA = X + (size_t)(m0 + (t >> 3)) * H_ + sj;
  const u16* gG = GTe + (size_t)(n0 + (t >> 3)) * H_ + sj;
  const u16* gU = UTe + (size_t)(n0 + (t >> 3)) * H_ + sj;
  u16* lA = sA + t * 8;
  u16* lG = sG + t * 8;
  u16* lU = sU + t * 8;

  const int l = t & 63, w = t >> 6;
  const int wm = (w & 1) * 64, wn = (w >> 1) * 32;
  // fragment read: row base + swizzled chunk offset; c0 for ks=0, c0^32 for ks=1
  const int c0 = (((l >> 4) ^ (l & 7))) * 8;
  const u16* fA = sA + (size_t)(wm + (l & 15)) * 64;
  const u16* fG = sG + (size_t)(wn + (l & 15)) * 64;
  const u16* fU = sU + (size_t)(wn + (l & 15)) * 64;

  f32x4 accG[4][2], accU[4][2];
#pragma unroll
  for (int mi = 0; mi < 4; ++mi)
#pragma unroll
    for (int ni = 0; ni < 2; ++ni) {
      accG[mi][ni] = (f32x4){0.f, 0.f, 0.f, 0.f};
      accU[mi][ni] = (f32x4){0.f, 0.f, 0.f, 0.f};
    }

  for (int k0 = 0; k0 < H_; k0 += 64) {
    async16(gA + k0, lA);
    async16(gA + 32 * H_ + k0, lA + 2048);
    async16(gA + 64 * H_ + k0, lA + 4096);
    async16(gA + 96 * H_ + k0, lA + 6144);
    async16(gG + k0, lG);
    async16(gG + 32 * H_ + k0, lG + 2048);
    async16(gU + k0, lU);
    async16(gU + 32 * H_ + k0, lU + 2048);
    __syncthreads();
#pragma unroll
    for (int ks = 0; ks < 2; ++ks) {
      const int co = c0 ^ (ks * 32);
      s16x8 aF[4], gF[2], uF[2];
#pragma unroll
      for (int mi = 0; mi < 4; ++mi) aF[mi] = *(const s16x8*)(fA + mi * 1024 + co);
#pragma unroll
      for (int ni = 0; ni < 2; ++ni) {
        gF[ni] = *(const s16x8*)(fG + ni * 1024 + co);
        uF[ni] = *(const s16x8*)(fU + ni * 1024 + co);
      }
#pragma unroll
      for (int mi = 0; mi < 4; ++mi)
#pragma unroll
        for (int ni = 0; ni < 2; ++ni) {
          accG[mi][ni] = __builtin_amdgcn_mfma_f32_16x16x32_bf16(aF[mi], gF[ni], accG[mi][ni], 0, 0, 0);
          accU[mi][ni] = __builtin_amdgcn_mfma_f32_16x16x32_bf16(aF[mi], uF[ni], accU[mi][ni], 0, 0, 0);
        }
    }
    __syncthreads();
  }

  const int colb = l & 15, rowb = (l >> 4) * 4;
#pragma unroll
  for (int mi = 0; mi < 4; ++mi)
#pragma unroll
    for (int ni = 0; ni < 2; ++ni) {
      const size_t gcol = (size_t)(n0 + wn + ni * 16 + colb);
#pragma unroll
      for (int r = 0; r < 4; ++r) {
        int grow = m0 + wm + mi * 16 + rowb + r;
        if (grow < seg_end) {
          float o1 = accG[mi][ni][r];
          float o2 = accU[mi][ni][r];
          float sv = o1 / (1.f + __expf(-o1));
          inter[(size_t)grow * I_ + gcol] = f2b(sv * o2);
        }
      }
    }
}

// ------- down-proj GEMM: 128x128 tile, BK=64 chunk-swizzled, split-K x2 -------
__global__ __launch_bounds__(256, 2) void gemm3_k(
    const u16* __restrict__ A, const u16* __restrict__ DT,
    const int* __restrict__ tpe, float* __restrict__ out,
    float* __restrict__ part) {
  __shared__ u16 sA[128 * 64];  // 16 KB
  __shared__ u16 sB[128 * 64];  // 16 KB
  const int t = threadIdx.x;
  const int m0 = blockIdx.y * 128;
  const int n0 = blockIdx.x * 128;
  const int ks = blockIdx.z;
  const int kbase = ks * (I_ / 2);

  int e = 0, seg_end = T_;
  {
    int s = 0;
    for (int i = 0; i < E_; ++i) {
      int c = tpe[i];
      if (m0 < s + c) { e = i; seg_end = s + c; break; }
      s += c;
    }
  }
  const u16* DTe = DT + (size_t)e * H_ * I_;

  const int sj = ((t & 7) ^ ((t >> 3) & 7)) * 8;
  const u16* gA = A + (size_t)(m0 + (t >> 3)) * I_ + kbase + sj;
  const u16* gB = DTe + (size_t)(n0 + (t >> 3)) * I_ + kbase + sj;
  u16* lA = sA + t * 8;
  u16* lB = sB + t * 8;

  const int l = t & 63, w = t >> 6;
  const int wm = (w & 1) * 64, wn = (w >> 1) * 64;
  const int c0 = (((l >> 4) ^ (l & 7))) * 8;
  const u16* fA = sA + (size_t)(wm + (l & 15)) * 64;
  const u16* fB = sB + (size_t)(wn + (l & 15)) * 64;

  f32x4 acc[4][4];
#pragma unroll
  for (int mi = 0; mi < 4; ++mi)
#pragma unroll
    for (int ni = 0; ni < 4; ++ni) acc[mi][ni] = (f32x4){0.f, 0.f, 0.f, 0.f};

  for (int k0 = 0; k0 < I_ / 2; k0 += 64) {
    async16(gA + k0, lA);
    async16(gA + 32 * I_ + k0, lA + 2048);
    async16(gA + 64 * I_ + k0, lA + 4096);
    async16(gA + 96 * I_ + k0, lA + 6144);
    async16(gB + k0, lB);
    async16(gB + 32 * I_ + k0, lB + 2048);
    async16(gB + 64 * I_ + k0, lB + 4096);
    async16(gB + 96 * I_ + k0, lB + 6144);
    __syncthreads();
#pragma unroll
    for (int kk = 0; kk < 2; ++kk) {
      const int co = c0 ^ (kk * 32);
      s16x8 aF[4], bF[4];
#pragma unroll
      for (int mi = 0; mi < 4; ++mi) aF[mi] = *(const s16x8*)(fA + mi * 1024 + co);
#pragma unroll
      for (int ni = 0; ni < 4; ++ni) bF[ni] = *(const s16x8*)(fB + ni * 1024 + co);
#pragma unroll
      for (int mi = 0; mi < 4; ++mi)
#pragma unroll
        for (int ni = 0; ni < 4; ++ni)
          acc[mi][ni] = __builtin_amdgcn_mfma_f32_16x16x32_bf16(aF[mi], bF[ni], acc[mi][ni], 0, 0, 0);
    }
    __syncthreads();
  }

  float* dst = ks ? part : out;
  const int colb = l & 15, rowb = (l >> 4) * 4;
#pragma unroll
  for (int mi = 0; mi < 4; ++mi)
#pragma unroll
    for (int ni = 0; ni < 4; ++ni) {
      const size_t gcol = (size_t)(n0 + wn + ni * 16 + colb);
#pragma unroll
      for (int r = 0; r < 4; ++r) {
        int grow = m0 + wm + mi * 16 + rowb + r;
        if (grow < seg_end) dst[(size_t)grow * H_ + gcol] = acc[mi][ni][r];
      }
    }
}

// ---------------- out += partial ----------------
__global__ __launch_bounds__(256) void add_k(float* __restrict__ out,
                                             const float* __restrict__ part) {
  size_t i = ((size_t)blockIdx.x * 256 + threadIdx.x) * 8;
  float4 a0 = *(float4*)(out + i);
  float4 a1 = *(float4*)(out + i + 4);
  float4 b0 = *(const float4*)(part + i);
  float4 b1 = *(const float4*)(part + i + 4);
  a0.x += b0.x; a0.y += b0.y; a0.z += b0.z; a0.w += b0.w;
  a1.x += b1.x; a1.y += b1.y; a1.z += b1.z; a1.w += b1.w;
  *(float4*)(out + i) = a0;
  *(float4*)(out + i + 4) = a1;
}

extern "C" void kernel_launch(void* const* d_in, const int* in_sizes, int n_in,
                              void* d_out, int out_size, void* d_ws, size_t ws_size,
                              hipStream_t stream) {
  const float* X = (const float*)d_in[0];
  const float* G = (const float*)d_in[1];
  const float* U = (const float*)d_in[2];
  const float* D = (const float*)d_in[3];
  const int* tpe = (const int*)d_in[4];
  float* out = (float*)d_out;

  const size_t W = (size_t)E_ * H_ * I_;
  if (ws_size < 3 * W * sizeof(u16)) return;
  u16* r0 = (u16*)d_ws;          // gateT, later downT
  u16* r1 = r0 + W;              // upT, later fp32 split-K partial (33.5 MB <= 46.1 MB)
  u16* r2 = r1 + W;              // inter [T][I] bf16
  u16* xb = (u16*)d_out;         // bf16 X staged in d_out; gemm3 ks=0 overwrites
  float* part = (float*)r1;

  convx_k<<<dim3((T_ * H_) / (256 * 8)), 256, 0, stream>>>(X, xb);
  tconvGU_k<<<dim3(I_ / 64, H_ / 64, E_ * 2), 256, 0, stream>>>(G, U, r0, r1);
  gemm12_k<<<dim3(I_ / 64, T_ / 128), 256, 0, stream>>>(xb, r0, r1, tpe, r2);
  tconvD_k<<<dim3(H_ / 64, I_ / 64, E_), 256, 0, stream>>>(D, r0);
  gemm3_k<<<dim3(H_ / 128, T_ / 128, 2), 256, 0, stream>>>(r2, r0, tpe, out, part);
  add_k<<<dim3((T_ * H_) / (256 * 8)), 256, 0, stream>>>(out, part);
}

// Round 6
// 477.069 us; speedup vs baseline: 1.1083x; 1.0200x over previous
//
#include <hip/hip_runtime.h>
#include <hip/hip_bf16.h>

// GroupedMLP: E=8, H=1024, I=2816, T=8192. fp32 in HBM, bf16 MFMA compute.
//   0) convx:   X fp32 -> xb bf16 (staged inside d_out; gemm3 overwrites later)
//   1) tconvGU: gate+up fp32 [E,H,I] -> gateT/upT bf16 [E,I,H] (zero-LDS, line-perfect)
//   2) gemm12:  inter = silu(xb@gate)*(xb@up)  [BK=64, chunk-swizzled; 854 TF anchor]
//   3) tconvD:  down fp32 [E,I,H] -> downT bf16 [E,H,I]
//   4) gemm3:   out = inter @ down, BM=128 BN=64 BK=64 (1024 blocks = 4/CU, no split-K)
// Chunk swizzle: LDS 16B-chunk for (row m, k-chunk j) lives at m*8 + (j ^ (m&7)).
// ws: 3 x 46,137,344 B (gateT/downT, upT, inter).

#define E_ 8
#define H_ 1024
#define I_ 2816
#define T_ 8192

typedef unsigned short u16;
typedef __attribute__((ext_vector_type(8))) short s16x8;
typedef __attribute__((ext_vector_type(8))) unsigned short u16x8;
typedef __attribute__((ext_vector_type(4))) float f32x4;

__device__ __forceinline__ void async16(const u16* g, u16* l) {
  __builtin_amdgcn_global_load_lds((__attribute__((address_space(1))) void*)g,
                                   (__attribute__((address_space(3))) void*)l, 16, 0, 0);
}

__device__ __forceinline__ u16 f2b(float f) {
  union { __hip_bfloat16 h; u16 u; } c;
  c.h = __float2bfloat16(f);
  return c.u;
}

// ---------------- convert X fp32 -> bf16 ----------------
__global__ __launch_bounds__(256) void convx_k(const float* __restrict__ x,
                                               u16* __restrict__ xb) {
  size_t i = ((size_t)blockIdx.x * 256 + threadIdx.x) * 8;
  float4 v0 = *(const float4*)(x + i);
  float4 v1 = *(const float4*)(x + i + 4);
  u16x8 b;
  b[0] = f2b(v0.x); b[1] = f2b(v0.y); b[2] = f2b(v0.z); b[3] = f2b(v0.w);
  b[4] = f2b(v1.x); b[5] = f2b(v1.y); b[6] = f2b(v1.z); b[7] = f2b(v1.w);
  *(u16x8*)(xb + i) = b;
}

// ---- zero-LDS transpose+convert: out[c][r] bf16 = in[r][c] fp32, 64x64 tile ----
// Lane owns column c = c0 + (t>>2), r-quarter q = t&3.
// Loads (16 scalar): instr j reads rows {q*8+j} over 16 consecutive cols/wave
//   -> 4 fully-covered 64B lines per wave-instr.
// Stores (2x 16B): 4 lanes of same c cover r 0..31 / 32..63 -> full 64B lines.
// No LDS, no barrier.
template <int R, int C>
__device__ __forceinline__ void tconv_tile(const float* __restrict__ in,
                                           u16* __restrict__ out,
                                           int bx, int by, int t) {
  const int c0 = bx * 64, r0 = by * 64;
  const int c = c0 + (t >> 2);
  const int rq = (t & 3) * 8;
  const float* p = in + (size_t)r0 * C + c;
  u16* o = out + (size_t)c * R + r0;
  u16x8 b;
#pragma unroll
  for (int j = 0; j < 8; ++j) b[j] = f2b(p[(size_t)(rq + j) * C]);
  *(u16x8*)(o + rq) = b;
#pragma unroll
  for (int j = 0; j < 8; ++j) b[j] = f2b(p[(size_t)(32 + rq + j) * C]);
  *(u16x8*)(o + 32 + rq) = b;
}

__global__ __launch_bounds__(256) void tconvGU_k(const float* __restrict__ G,
                                                 const float* __restrict__ U,
                                                 u16* __restrict__ GT,
                                                 u16* __restrict__ UT) {
  const int z = blockIdx.z;
  const size_t eoff = (size_t)(z >> 1) * (size_t)H_ * I_;
  const float* in = ((z & 1) ? U : G) + eoff;
  u16* out = ((z & 1) ? UT : GT) + eoff;
  tconv_tile<H_, I_>(in, out, blockIdx.x, blockIdx.y, threadIdx.x);
}

__global__ __launch_bounds__(256) void tconvD_k(const float* __restrict__ D,
                                                u16* __restrict__ DT) {
  const size_t eoff = (size_t)blockIdx.z * (size_t)H_ * I_;
  tconv_tile<I_, H_>(D + eoff, DT + eoff, blockIdx.x, blockIdx.y, threadIdx.x);
}

// ---------------- fused gate/up GEMM + SwiGLU, BK=64, chunk-swizzled (ANCHOR) ----------------
__global__ __launch_bounds__(256, 2) void gemm12_k(
    const u16* __restrict__ X, const u16* __restrict__ GT,
    const u16* __restrict__ UT, const int* __restrict__ tpe,
    u16* __restrict__ inter) {
  __shared__ u16 sA[128 * 64];
  __shared__ u16 sG[64 * 64];
  __shared__ u16 sU[64 * 64];
  const int t = threadIdx.x;
  const int m0 = blockIdx.y * 128;
  const int n0 = blockIdx.x * 64;

  int e = 0, seg_end = T_;
  {
    int s = 0;
    for (int i = 0; i < E_; ++i) {
      int c = tpe[i];
      if (m0 < s + c) { e = i; seg_end = s + c; break; }
      s += c;
    }
  }
  const u16* GTe = GT + (size_t)e * I_ * H_;
  const u16* UTe = UT + (size_t)e * I_ * H_;

  const int sj = ((t & 7) ^ ((t >> 3) & 7)) * 8;
  const u16* gA = X + (size_t)(m0 + (t >> 3)) * H_ + sj;
  const u16* gG = GTe + (size_t)(n0 + (t >> 3)) * H_ + sj;
  const u16* gU = UTe + (size_t)(n0 + (t >> 3)) * H_ + sj;
  u16* lA = sA + t * 8;
  u16* lG = sG + t * 8;
  u16* lU = sU + t * 8;

  const int l = t & 63, w = t >> 6;
  const int wm = (w & 1) * 64, wn = (w >> 1) * 32;
  const int c0 = (((l >> 4) ^ (l & 7))) * 8;
  const u16* fA = sA + (size_t)(wm + (l & 15)) * 64;
  const u16* fG = sG + (size_t)(wn + (l & 15)) * 64;
  const u16* fU = sU + (size_t)(wn + (l & 15)) * 64;

  f32x4 accG[4][2], accU[4][2];
#pragma unroll
  for (int mi = 0; mi < 4; ++mi)
#pragma unroll
    for (int ni = 0; ni < 2; ++ni) {
      accG[mi][ni] = (f32x4){0.f, 0.f, 0.f, 0.f};
      accU[mi][ni] = (f32x4){0.f, 0.f, 0.f, 0.f};
    }

  for (int k0 = 0; k0 < H_; k0 += 64) {
    async16(gA + k0, lA);
    async16(gA + 32 * H_ + k0, lA + 2048);
    async16(gA + 64 * H_ + k0, lA + 4096);
    async16(gA + 96 * H_ + k0, lA + 6144);
    async16(gG + k0, lG);
    async16(gG + 32 * H_ + k0, lG + 2048);
    async16(gU + k0, lU);
    async16(gU + 32 * H_ + k0, lU + 2048);
    __syncthreads();
#pragma unroll
    for (int ks = 0; ks < 2; ++ks) {
      const int co = c0 ^ (ks * 32);
      s16x8 aF[4], gF[2], uF[2];
#pragma unroll
      for (int mi = 0; mi < 4; ++mi) aF[mi] = *(const s16x8*)(fA + mi * 1024 + co);
#pragma unroll
      for (int ni = 0; ni < 2; ++ni) {
        gF[ni] = *(const s16x8*)(fG + ni * 1024 + co);
        uF[ni] = *(const s16x8*)(fU + ni * 1024 + co);
      }
#pragma unroll
      for (int mi = 0; mi < 4; ++mi)
#pragma unroll
        for (int ni = 0; ni < 2; ++ni) {
          accG[mi][ni] = __builtin_amdgcn_mfma_f32_16x16x32_bf16(aF[mi], gF[ni], accG[mi][ni], 0, 0, 0);
          accU[mi][ni] = __builtin_amdgcn_mfma_f32_16x16x32_bf16(aF[mi], uF[ni], accU[mi][ni], 0, 0, 0);
        }
    }
    __syncthreads();
  }

  const int colb = l & 15, rowb = (l >> 4) * 4;
#pragma unroll
  for (int mi = 0; mi < 4; ++mi)
#pragma unroll
    for (int ni = 0; ni < 2; ++ni) {
      const size_t gcol = (size_t)(n0 + wn + ni * 16 + colb);
#pragma unroll
      for (int r = 0; r < 4; ++r) {
        int grow = m0 + wm + mi * 16 + rowb + r;
        if (grow < seg_end) {
          float o1 = accG[mi][ni][r];
          float o2 = accU[mi][ni][r];
          float sv = o1 / (1.f + __expf(-o1));
          inter[(size_t)grow * I_ + gcol] = f2b(sv * o2);
        }
      }
    }
}

// ------- down-proj GEMM: BM=128, BN=64, BK=64 chunk-swizzled, no split-K -------
// grid 16 x 64 = 1024 blocks = 4/CU; per-wave 64x32 (the 854 TF gemm12 shape).
__global__ __launch_bounds__(256, 2) void gemm3_k(
    const u16* __restrict__ A, const u16* __restrict__ DT,
    const int* __restrict__ tpe, float* __restrict__ out) {
  __shared__ u16 sA[128 * 64];  // 16 KB
  __shared__ u16 sB[64 * 64];   // 8 KB
  const int t = threadIdx.x;
  const int m0 = blockIdx.y * 128;
  const int n0 = blockIdx.x * 64;

  int e = 0, seg_end = T_;
  {
    int s = 0;
    for (int i = 0; i < E_; ++i) {
      int c = tpe[i];
      if (m0 < s + c) { e = i; seg_end = s + c; break; }
      s += c;
    }
  }
  const u16* DTe = DT + (size_t)e * H_ * I_;

  const int sj = ((t & 7) ^ ((t >> 3) & 7)) * 8;
  const u16* gA = A + (size_t)(m0 + (t >> 3)) * I_ + sj;
  const u16* gB = DTe + (size_t)(n0 + (t >> 3)) * I_ + sj;
  u16* lA = sA + t * 8;
  u16* lB = sB + t * 8;

  const int l = t & 63, w = t >> 6;
  const int wm = (w & 1) * 64, wn = (w >> 1) * 32;
  const int c0 = (((l >> 4) ^ (l & 7))) * 8;
  const u16* fA = sA + (size_t)(wm + (l & 15)) * 64;
  const u16* fB = sB + (size_t)(wn + (l & 15)) * 64;

  f32x4 acc[4][2];
#pragma unroll
  for (int mi = 0; mi < 4; ++mi)
#pragma unroll
    for (int ni = 0; ni < 2; ++ni) acc[mi][ni] = (f32x4){0.f, 0.f, 0.f, 0.f};

  for (int k0 = 0; k0 < I_; k0 += 64) {
    async16(gA + k0, lA);
    async16(gA + 32 * I_ + k0, lA + 2048);
    async16(gA + 64 * I_ + k0, lA + 4096);
    async16(gA + 96 * I_ + k0, lA + 6144);
    async16(gB + k0, lB);
    async16(gB + 32 * I_ + k0, lB + 2048);
    __syncthreads();
#pragma unroll
    for (int ks = 0; ks < 2; ++ks) {
      const int co = c0 ^ (ks * 32);
      s16x8 aF[4], bF[2];
#pragma unroll
      for (int mi = 0; mi < 4; ++mi) aF[mi] = *(const s16x8*)(fA + mi * 1024 + co);
#pragma unroll
      for (int ni = 0; ni < 2; ++ni) bF[ni] = *(const s16x8*)(fB + ni * 1024 + co);
#pragma unroll
      for (int mi = 0; mi < 4; ++mi)
#pragma unroll
        for (int ni = 0; ni < 2; ++ni)
          acc[mi][ni] = __builtin_amdgcn_mfma_f32_16x16x32_bf16(aF[mi], bF[ni], acc[mi][ni], 0, 0, 0);
    }
    __syncthreads();
  }

  const int colb = l & 15, rowb = (l >> 4) * 4;
#pragma unroll
  for (int mi = 0; mi < 4; ++mi)
#pragma unroll
    for (int ni = 0; ni < 2; ++ni) {
      const size_t gcol = (size_t)(n0 + wn + ni * 16 + colb);
#pragma unroll
      for (int r = 0; r < 4; ++r) {
        int grow = m0 + wm + mi * 16 + rowb + r;
        if (grow < seg_end) out[(size_t)grow * H_ + gcol] = acc[mi][ni][r];
      }
    }
}

extern "C" void kernel_launch(void* const* d_in, const int* in_sizes, int n_in,
                              void* d_out, int out_size, void* d_ws, size_t ws_size,
                              hipStream_t stream) {
  const float* X = (const float*)d_in[0];
  const float* G = (const float*)d_in[1];
  const float* U = (const float*)d_in[2];
  const float* D = (const float*)d_in[3];
  const int* tpe = (const int*)d_in[4];
  float* out = (float*)d_out;

  const size_t W = (size_t)E_ * H_ * I_;
  if (ws_size < 3 * W * sizeof(u16)) return;
  u16* r0 = (u16*)d_ws;   // gateT, later downT
  u16* r1 = r0 + W;       // upT
  u16* r2 = r1 + W;       // inter [T][I] bf16
  u16* xb = (u16*)d_out;  // bf16 X staged in d_out; dead after gemm12; gemm3 overwrites

  convx_k<<<dim3((T_ * H_) / (256 * 8)), 256, 0, stream>>>(X, xb);
  tconvGU_k<<<dim3(I_ / 64, H_ / 64, E_ * 2), 256, 0, stream>>>(G, U, r0, r1);
  gemm12_k<<<dim3(I_ / 64, T_ / 128), 256, 0, stream>>>(xb, r0, r1, tpe, r2);
  tconvD_k<<<dim3(H_ / 64, I_ / 64, E_), 256, 0, stream>>>(D, r0);
  gemm3_k<<<dim3(H_ / 64, T_ / 128), 256, 0, stream>>>(r2, r0, tpe, out);
}